// Round 5
// baseline (397.024 us; speedup 1.0000x reference)
//
#include <hip/hip_runtime.h>
#include <hip/hip_bf16.h>

#define BB 4
#define PP 2048
#define CCLUS 512
#define DD 1024
#define HH 16
#define DHH 64

typedef __attribute__((ext_vector_type(8))) short short8;
typedef __attribute__((ext_vector_type(4))) float floatx4;
typedef unsigned short u16;
typedef unsigned int u32;
typedef unsigned long long u64;

__device__ __forceinline__ float bf2f(u16 u) {
  union { u32 i; float f; } v; v.i = ((u32)u) << 16; return v.f;
}
__device__ __forceinline__ u16 f2bf(float f) {
  union { float f; u32 i; } v; v.f = f;
  u32 x = v.i;
  return (u16)((x + 0x7fffu + ((x >> 16) & 1u)) >> 16);  // RNE
}
__device__ __forceinline__ u64 pack4(float a, float b, float c, float d) {
  return (u64)f2bf(a) | ((u64)f2bf(b) << 16) | ((u64)f2bf(c) << 32) | ((u64)f2bf(d) << 48);
}

__device__ __forceinline__ floatx4 mfma16(short8 a, short8 b, floatx4 c) {
  return __builtin_amdgcn_mfma_f32_16x16x32_bf16(a, b, c, 0, 0, 0);
}

// ---------------- transpose+cast Wq/Wk/Wv (1024x1024 f32 -> bf16^T) ----------------
__global__ __launch_bounds__(1024) void transpose3_k(
    const float* __restrict__ Wq, const float* __restrict__ Wk, const float* __restrict__ Wv,
    u16* __restrict__ WqT, u16* __restrict__ WkT, u16* __restrict__ WvT) {
  __shared__ u16 tile[32][33];
  const int z = blockIdx.z;
  const float* src = (z == 0) ? Wq : (z == 1) ? Wk : Wv;
  u16* dst = (z == 0) ? WqT : (z == 1) ? WkT : WvT;
  int x = blockIdx.x * 32 + threadIdx.x;
  int y = blockIdx.y * 32 + threadIdx.y;
  tile[threadIdx.y][threadIdx.x] = f2bf(src[y * DD + x]);
  __syncthreads();
  x = blockIdx.y * 32 + threadIdx.x;
  y = blockIdx.x * 32 + threadIdx.y;
  dst[y * DD + x] = tile[threadIdx.x][threadIdx.y];
}

// ---------------- fused QKV projection GEMM (explicit staging) ----------------
// C[M,1024] = (A_f32[M,1024] @ BT_bf16[1024,1024]^T + bias) * scale, bf16 out.
// 128x128 tile, BK=32, 4 waves each 64x64. A staged f32->bf16 in-kernel.
__global__ __launch_bounds__(256) void qkv_gemm2(
    const float* __restrict__ para, const float* __restrict__ cluster,
    const u16* __restrict__ WqT, const u16* __restrict__ WkT, const u16* __restrict__ WvT,
    const float* __restrict__ bq, const float* __restrict__ bk, const float* __restrict__ bv,
    u16* __restrict__ Qb, u16* __restrict__ Kb, u16* __restrict__ Vb) {
  const int z = blockIdx.z;
  const float* A; const u16* BT; const float* bias; u16* Cout; float scale; int mtiles;
  if (z == 0)      { A = para;    BT = WqT; bias = bq; Cout = Qb; scale = 0.125f; mtiles = 64; }
  else if (z == 1) { A = cluster; BT = WkT; bias = bk; Cout = Kb; scale = 1.0f;   mtiles = 16; }
  else             { A = cluster; BT = WvT; bias = bv; Cout = Vb; scale = 1.0f;   mtiles = 16; }
  if (blockIdx.x >= mtiles) return;

  __shared__ __align__(16) u16 As[128 * 32];   // [row 0..128)[k 0..32)
  __shared__ __align__(16) u16 Bs[128 * 32];   // [ncol 0..128)[k 0..32)

  const int tid = threadIdx.x;
  const int w = tid >> 6, lane = tid & 63, quad = lane >> 4, cidx = lane & 15;
  const int wy = w >> 1, wx = w & 1;
  const int m0 = blockIdx.x * 128, n0 = blockIdx.y * 128;

  floatx4 acc[4][4];
#pragma unroll
  for (int i = 0; i < 4; i++)
#pragma unroll
    for (int j = 0; j < 4; j++) acc[i][j] = (floatx4){0.f, 0.f, 0.f, 0.f};

  const int rowA = tid >> 1, colA = (tid & 1) * 16;
  const int rowB = tid >> 2, kcB = (tid & 3) * 8;

  const float* Abase = A + (size_t)(m0 + rowA) * 1024 + colA;
  const u16* Bbase = BT + (size_t)n0 * 1024;

  for (int kt = 0; kt < 32; kt++) {
    const float* Ag = Abase + kt * 32;
    float4 fa = *(const float4*)(Ag + 0);
    float4 fb = *(const float4*)(Ag + 4);
    float4 fc = *(const float4*)(Ag + 8);
    float4 fd = *(const float4*)(Ag + 12);
    u16* Aw = &As[rowA * 32 + colA];
    *(u64*)(Aw + 0)  = pack4(fa.x, fa.y, fa.z, fa.w);
    *(u64*)(Aw + 4)  = pack4(fb.x, fb.y, fb.z, fb.w);
    *(u64*)(Aw + 8)  = pack4(fc.x, fc.y, fc.z, fc.w);
    *(u64*)(Aw + 12) = pack4(fd.x, fd.y, fd.z, fd.w);
    const u16* Bg0 = Bbase + (size_t)rowB * 1024 + kt * 32 + kcB;
    const u16* Bg1 = Bbase + (size_t)(rowB + 64) * 1024 + kt * 32 + kcB;
    *(short8*)&Bs[rowB * 32 + kcB] = *(const short8*)Bg0;
    *(short8*)&Bs[(rowB + 64) * 32 + kcB] = *(const short8*)Bg1;
    __syncthreads();

    short8 af[4], bfr[4];
#pragma unroll
    for (int i = 0; i < 4; i++) {
      int ra = wy * 64 + i * 16 + cidx;
      af[i] = *(const short8*)&As[ra * 32 + quad * 8];
      int rb = wx * 64 + i * 16 + cidx;
      bfr[i] = *(const short8*)&Bs[rb * 32 + quad * 8];
    }
#pragma unroll
    for (int mi = 0; mi < 4; mi++)
#pragma unroll
      for (int ni = 0; ni < 4; ni++)
        acc[mi][ni] = mfma16(af[mi], bfr[ni], acc[mi][ni]);
    __syncthreads();
  }

#pragma unroll
  for (int ni = 0; ni < 4; ni++) {
    const int ncol = n0 + wx * 64 + ni * 16 + cidx;
    const float bvv = bias[ncol];
#pragma unroll
    for (int mi = 0; mi < 4; mi++) {
      const int mrow = m0 + wy * 64 + mi * 16 + quad * 4;
#pragma unroll
      for (int r = 0; r < 4; r++) {
        float v = (acc[mi][ni][r] + bvv) * scale;
        Cout[(size_t)(mrow + r) * 1024 + ncol] = f2bf(v);
      }
    }
  }
}

// ---------------- fused masked attention (scores+softmax+edge+PV) ----------------
// block: (b, h, 64 P-rows); 4 waves, wave w owns rows [w*16, w*16+16).
// ctx written as FLOAT32 (reference output dtype) into d_out.
__global__ __launch_bounds__(256) void attn_k(
    const u16* __restrict__ Qb, const u16* __restrict__ Kb, const u16* __restrict__ Vb,
    const float* __restrict__ edge, float* __restrict__ ctx) {
  const int b = blockIdx.z, h = blockIdx.y, p0 = blockIdx.x * 64;
  const int tid = threadIdx.x;
  const int w = tid >> 6, lane = tid & 63, quad = lane >> 4, cidx = lane & 15;

  __shared__ __align__(16) u16 Qs[64][72];
  __shared__ __align__(16) u16 VTs[64][72];       // [d_local][c_local] transposed V chunk
  __shared__ __align__(16) u16 attnS[4][16][40];  // per-wave C->A layout round-trip

  // stage Q tile [64 p][64 d]
#pragma unroll
  for (int i = 0; i < 2; i++) {
    int ch = tid + i * 256;
    int r = ch >> 3, c8 = ch & 7;
    const u16* g = Qb + ((size_t)(b * PP + p0 + r) * DD + h * DHH + c8 * 8);
    *(short8*)&Qs[r][c8 * 8] = *(const short8*)g;
  }
  __syncthreads();

  const int qrow = w * 16 + cidx;  // A-frag: m = lane&15
  const short8 qf0 = *(const short8*)&Qs[qrow][quad * 8];
  const short8 qf1 = *(const short8*)&Qs[qrow][32 + quad * 8];

  const u16* Kbh = Kb + ((size_t)b * CCLUS * DD + h * DHH);
  const float* Ebp = edge + (size_t)(b * PP + p0 + w * 16) * CCLUS;

  float mrow[4] = {-1e18f, -1e18f, -1e18f, -1e18f};
  float srow[4] = {0.f, 0.f, 0.f, 0.f};

  // pass 1: online max/sum. lane's scores: row=quad*4+r, col=ct*16+cidx
  for (int ct = 0; ct < 32; ct++) {
    const int c = ct * 16 + cidx;
    const u16* krow = Kbh + (size_t)c * DD;  // B-frag: n=lane&15, k=quad*8+j
    short8 kf0 = *(const short8*)(krow + quad * 8);
    short8 kf1 = *(const short8*)(krow + 32 + quad * 8);
    floatx4 s4 = {0.f, 0.f, 0.f, 0.f};
    s4 = mfma16(qf0, kf0, s4);
    s4 = mfma16(qf1, kf1, s4);
#pragma unroll
    for (int r = 0; r < 4; r++) {
      float e = Ebp[(quad * 4 + r) * CCLUS + c];
      float sv = s4[r];
      float sc = (e > 0.f && sv == sv) ? fminf(sv, 1e30f) : -1e18f;
      float mn = fmaxf(mrow[r], sc);
      srow[r] = srow[r] * __expf(mrow[r] - mn) + __expf(sc - mn);
      mrow[r] = mn;
    }
  }
  // combine 16 lanes of each quad (same 4 rows, disjoint cols)
#pragma unroll
  for (int off = 1; off < 16; off <<= 1) {
#pragma unroll
    for (int r = 0; r < 4; r++) {
      float mo = __shfl_xor(mrow[r], off, 64);
      float so = __shfl_xor(srow[r], off, 64);
      float mn = fmaxf(mrow[r], mo);
      srow[r] = srow[r] * __expf(mrow[r] - mn) + so * __expf(mo - mn);
      mrow[r] = mn;
    }
  }
  float sinv[4];
#pragma unroll
  for (int r = 0; r < 4; r++) sinv[r] = (srow[r] > 0.f) ? 1.0f / srow[r] : 0.f;

  floatx4 oacc[4];
#pragma unroll
  for (int nt = 0; nt < 4; nt++) oacc[nt] = (floatx4){0.f, 0.f, 0.f, 0.f};

  // pass 2: per 64-c chunk, stage V transposed, recompute attn, PV-MFMA
  for (int cc2 = 0; cc2 < 8; cc2++) {
    __syncthreads();  // previous chunk's VTs reads done
#pragma unroll
    for (int i = 0; i < 2; i++) {
      int g = i * 256 + tid;
      int cl = g & 63, dblk = g >> 6;
      const u16* vg = Vb + ((size_t)(b * CCLUS + cc2 * 64 + cl) * DD + h * DHH + dblk * 8);
      short8 vv = *(const short8*)vg;
#pragma unroll
      for (int j = 0; j < 8; j++) VTs[dblk * 8 + j][cl] = ((const u16*)&vv)[j];
    }
    __syncthreads();

    for (int s = 0; s < 2; s++) {
#pragma unroll
      for (int t2 = 0; t2 < 2; t2++) {
        const int c = (cc2 * 4 + s * 2 + t2) * 16 + cidx;
        const u16* krow = Kbh + (size_t)c * DD;
        short8 kf0 = *(const short8*)(krow + quad * 8);
        short8 kf1 = *(const short8*)(krow + 32 + quad * 8);
        floatx4 s4 = {0.f, 0.f, 0.f, 0.f};
        s4 = mfma16(qf0, kf0, s4);
        s4 = mfma16(qf1, kf1, s4);
#pragma unroll
        for (int r = 0; r < 4; r++) {
          float e = Ebp[(quad * 4 + r) * CCLUS + c];
          float sv = s4[r];
          float a = (e > 0.f && sv == sv)
                        ? (__expf(fminf(sv, 1e30f) - mrow[r]) * sinv[r] * e) : 0.f;
          attnS[w][quad * 4 + r][t2 * 16 + cidx] = f2bf(a);
        }
      }
      __syncthreads();  // attnS written
      // A-layout read: A[m=lane&15][k=quad*8+j]
      short8 afr = *(const short8*)&attnS[w][cidx][quad * 8];
#pragma unroll
      for (int nt = 0; nt < 4; nt++) {
        short8 bfr = *(const short8*)&VTs[nt * 16 + cidx][s * 32 + quad * 8];
        oacc[nt] = mfma16(afr, bfr, oacc[nt]);
      }
      __syncthreads();  // attnS reads done before next s-iteration rewrites
    }
  }

#pragma unroll
  for (int nt = 0; nt < 4; nt++)
#pragma unroll
    for (int r = 0; r < 4; r++) {
      size_t off = (size_t)(b * PP + p0 + w * 16 + quad * 4 + r) * DD + h * DHH + nt * 16 + cidx;
      ctx[off] = oacc[nt][r];
    }
}

// ---------------- LayerNorm over D=1024 (f32 in-place on d_out) ----------------
__global__ __launch_bounds__(256) void ln_k(
    float* buf, const float* __restrict__ gamma, const float* __restrict__ beta) {
  const int row = blockIdx.x, tid = threadIdx.x;
  const int w = tid >> 6, lane = tid & 63;
  float* x = buf + (size_t)row * DD + tid * 4;
  float4 v = *(const float4*)x;
  float s = v.x + v.y + v.z + v.w;
  float sq = v.x * v.x + v.y * v.y + v.z * v.z + v.w * v.w;
#pragma unroll
  for (int off = 1; off < 64; off <<= 1) {
    s += __shfl_xor(s, off, 64);
    sq += __shfl_xor(sq, off, 64);
  }
  __shared__ float red[8];
  if (lane == 0) { red[w] = s; red[4 + w] = sq; }
  __syncthreads();
  s = red[0] + red[1] + red[2] + red[3];
  sq = red[4] + red[5] + red[6] + red[7];
  const float mu = s * (1.f / 1024.f);
  const float var = sq * (1.f / 1024.f) - mu * mu;
  const float rs = rsqrtf(fmaxf(var, 0.f) + 1e-6f);
  const float4 gr = *(const float4*)(gamma + tid * 4);
  const float4 br = *(const float4*)(beta + tid * 4);
  float4 y;
  y.x = (v.x - mu) * rs * gr.x + br.x;
  y.y = (v.y - mu) * rs * gr.y + br.y;
  y.z = (v.z - mu) * rs * gr.z + br.z;
  y.w = (v.w - mu) * rs * gr.w + br.w;
  *(float4*)x = y;
}

extern "C" void kernel_launch(void* const* d_in, const int* in_sizes, int n_in,
                              void* d_out, int out_size, void* d_ws, size_t ws_size,
                              hipStream_t stream) {
  // reference dtypes: ALL inputs float32; output float32 (ref returns f32)
  const float* para    = (const float*)d_in[0];
  const float* cluster = (const float*)d_in[1];
  const float* edge    = (const float*)d_in[2];
  const float* Wq      = (const float*)d_in[3];
  const float* bq      = (const float*)d_in[4];
  const float* Wk      = (const float*)d_in[5];
  const float* bk      = (const float*)d_in[6];
  const float* Wv      = (const float*)d_in[7];
  const float* bv      = (const float*)d_in[8];
  const float* gamma   = (const float*)d_in[9];
  const float* beta    = (const float*)d_in[10];
  float* out = (float*)d_out;   // 8M f32; ctx lives here (attn writes f32, LN in-place)

  // bf16 workspace: 15M u16 = 30 MB
  u16* WqT = (u16*)d_ws;                        // 1M
  u16* WkT = WqT + (size_t)1024 * 1024;         // 1M
  u16* WvT = WkT + (size_t)1024 * 1024;         // 1M
  u16* Qb  = WvT + (size_t)1024 * 1024;         // 8M
  u16* Kb  = Qb  + (size_t)8192 * 1024;         // 2M
  u16* Vb  = Kb  + (size_t)2048 * 1024;         // 2M

  transpose3_k<<<dim3(32, 32, 3), dim3(32, 32), 0, stream>>>(Wq, Wk, Wv, WqT, WkT, WvT);
  qkv_gemm2<<<dim3(64, 8, 3), dim3(256), 0, stream>>>(para, cluster, WqT, WkT, WvT,
                                                      bq, bk, bv, Qb, Kb, Vb);
  attn_k<<<dim3(PP / 64, HH, BB), dim3(256), 0, stream>>>(Qb, Kb, Vb, edge, out);
  ln_k<<<dim3(BB * PP), dim3(256), 0, stream>>>(out, gamma, beta);
}

// Round 7
// 307.791 us; speedup vs baseline: 1.2899x; 1.2899x over previous
//
#include <hip/hip_runtime.h>
#include <hip/hip_bf16.h>

#define BB 4
#define PP 2048
#define CCLUS 512
#define DD 1024
#define HH 16
#define DHH 64

typedef __attribute__((ext_vector_type(8))) short short8;
typedef __attribute__((ext_vector_type(4))) float floatx4;
typedef __attribute__((ext_vector_type(2))) __fp16 fp16x2;
typedef unsigned short u16;
typedef unsigned int u32;
typedef unsigned long long u64;

__device__ __forceinline__ float bf2f(u16 u) {
  union { u32 i; float f; } v; v.i = ((u32)u) << 16; return v.f;
}
__device__ __forceinline__ u16 f2bf(float f) {
  union { float f; u32 i; } v; v.f = f;
  u32 x = v.i;
  return (u16)((x + 0x7fffu + ((x >> 16) & 1u)) >> 16);  // RNE
}
__device__ __forceinline__ u64 pack4(float a, float b, float c, float d) {
  return (u64)f2bf(a) | ((u64)f2bf(b) << 16) | ((u64)f2bf(c) << 32) | ((u64)f2bf(d) << 48);
}
__device__ __forceinline__ u32 packh2(float a, float b) {
  union { fp16x2 h; u32 u; } v;
  v.h = __builtin_amdgcn_cvt_pkrtz(a, b);  // v_cvt_pkrtz_f16_f32
  return v.u;
}
__device__ __forceinline__ float h2f(u32 x) {
  union { u16 u; __fp16 h; } v; v.u = (u16)x; return (float)v.h;
}

__device__ __forceinline__ floatx4 mfma16(short8 a, short8 b, floatx4 c) {
  return __builtin_amdgcn_mfma_f32_16x16x32_bf16(a, b, c, 0, 0, 0);
}

// async global->LDS, 16B/lane; LDS dest = wave-uniform base + lane*16 (m97)
__device__ __forceinline__ void gload_lds16(const u16* g, u16* l) {
  __builtin_amdgcn_global_load_lds(
      (const __attribute__((address_space(1))) u32*)g,
      (__attribute__((address_space(3))) u32*)l, 16, 0, 0);
}

// ---------------- f32 -> bf16 cast for para & cluster ----------------
__global__ __launch_bounds__(256) void cast_k(
    const float* __restrict__ para, const float* __restrict__ cluster,
    u16* __restrict__ Ap, u16* __restrict__ Ac) {
  const int NP4 = (BB * PP * DD) / 4;
  const int NC4 = (BB * CCLUS * DD) / 4;
  const int stride = gridDim.x * blockDim.x;
  for (int i = blockIdx.x * blockDim.x + threadIdx.x; i < NP4 + NC4; i += stride) {
    const float* src; u16* dst; int j;
    if (i < NP4) { src = para; dst = Ap; j = i; }
    else         { src = cluster; dst = Ac; j = i - NP4; }
    const float4 v = *(const float4*)(src + (size_t)j * 4);
    *(u64*)(dst + (size_t)j * 4) = pack4(v.x, v.y, v.z, v.w);
  }
}

// ---------------- transpose+cast Wq/Wk/Wv (1024x1024 f32 -> bf16^T) ----------------
__global__ __launch_bounds__(1024) void transpose3_k(
    const float* __restrict__ Wq, const float* __restrict__ Wk, const float* __restrict__ Wv,
    u16* __restrict__ WqT, u16* __restrict__ WkT, u16* __restrict__ WvT) {
  __shared__ u16 tile[32][33];
  const int z = blockIdx.z;
  const float* src = (z == 0) ? Wq : (z == 1) ? Wk : Wv;
  u16* dst = (z == 0) ? WqT : (z == 1) ? WkT : WvT;
  int x = blockIdx.x * 32 + threadIdx.x;
  int y = blockIdx.y * 32 + threadIdx.y;
  tile[threadIdx.y][threadIdx.x] = f2bf(src[y * DD + x]);
  __syncthreads();
  x = blockIdx.y * 32 + threadIdx.x;
  y = blockIdx.x * 32 + threadIdx.y;
  dst[y * DD + x] = tile[threadIdx.x][threadIdx.y];
}

// ---------------- fused QKV GEMM (m97 global_load_lds staging) ----------------
// C[M,1024] = (A_bf16 @ BT_bf16^T + bias)*scale, bf16 out. 128x128, BK=32.
// packed grid.x=96: [0,64)=Q, [64,80)=K, [80,96)=V.
__global__ __launch_bounds__(256) void qkv_gemm3(
    const u16* __restrict__ Ap, const u16* __restrict__ Ac,
    const u16* __restrict__ WqT, const u16* __restrict__ WkT, const u16* __restrict__ WvT,
    const float* __restrict__ bq, const float* __restrict__ bk, const float* __restrict__ bv,
    u16* __restrict__ Qb, u16* __restrict__ Kb, u16* __restrict__ Vb) {
  const int bx = blockIdx.x;
  const u16* A; const u16* BT; const float* bias; u16* Cout; float scale; int mt;
  if (bx < 64)      { A = Ap; BT = WqT; bias = bq; Cout = Qb; scale = 0.125f; mt = bx; }
  else if (bx < 80) { A = Ac; BT = WkT; bias = bk; Cout = Kb; scale = 1.0f;   mt = bx - 64; }
  else              { A = Ac; BT = WvT; bias = bv; Cout = Vb; scale = 1.0f;   mt = bx - 80; }

  __shared__ __align__(16) u16 As[128 * 32];
  __shared__ __align__(16) u16 Bs[128 * 32];

  const int tid = threadIdx.x;
  const int w = tid >> 6, lane = tid & 63, quad = lane >> 4, cidx = lane & 15;
  const int wy = w >> 1, wx = w & 1;
  const int m0 = mt * 128, n0 = blockIdx.y * 128;

  floatx4 acc[4][4];
#pragma unroll
  for (int i = 0; i < 4; i++)
#pragma unroll
    for (int j = 0; j < 4; j++) acc[i][j] = (floatx4){0.f, 0.f, 0.f, 0.f};

  // slot ch = tid (+256): row=ch>>2, kc=ch&3; LDS byte off = ch*16 (lane-contiguous)
  const int row0 = tid >> 2, kc0 = tid & 3;
  const int offG0 = row0 * 1024 + kc0 * 8;
  const int offG1 = (row0 + 64) * 1024 + kc0 * 8;
  u16* ldsA0 = As + (size_t)(w * 64) * 8;
  u16* ldsA1 = As + (size_t)(w * 64 + 256) * 8;
  u16* ldsB0 = Bs + (size_t)(w * 64) * 8;
  u16* ldsB1 = Bs + (size_t)(w * 64 + 256) * 8;

  const u16* Abase = A + (size_t)m0 * 1024;
  const u16* Bbase = BT + (size_t)n0 * 1024;

  for (int kt = 0; kt < 32; kt++) {
    const u16* Ak = Abase + kt * 32;
    const u16* Bk = Bbase + kt * 32;
    gload_lds16(Ak + offG0, ldsA0);
    gload_lds16(Ak + offG1, ldsA1);
    gload_lds16(Bk + offG0, ldsB0);
    gload_lds16(Bk + offG1, ldsB1);
    __syncthreads();

    short8 af[4], bfr[4];
#pragma unroll
    for (int i = 0; i < 4; i++) {
      int ra = wy * 64 + i * 16 + cidx;
      af[i] = *(const short8*)&As[ra * 32 + quad * 8];
      int rb = wx * 64 + i * 16 + cidx;
      bfr[i] = *(const short8*)&Bs[rb * 32 + quad * 8];
    }
#pragma unroll
    for (int mi = 0; mi < 4; mi++)
#pragma unroll
      for (int ni = 0; ni < 4; ni++)
        acc[mi][ni] = mfma16(af[mi], bfr[ni], acc[mi][ni]);
    __syncthreads();
  }

#pragma unroll
  for (int ni = 0; ni < 4; ni++) {
    const int ncol = n0 + wx * 64 + ni * 16 + cidx;
    const float bvv = bias[ncol];
#pragma unroll
    for (int mi = 0; mi < 4; mi++) {
      const int mrow = m0 + wy * 64 + mi * 16 + quad * 4;
#pragma unroll
      for (int r = 0; r < 4; r++) {
        float v = (acc[mi][ni][r] + bvv) * scale;
        Cout[(size_t)(mrow + r) * 1024 + ncol] = f2bf(v);
      }
    }
  }
}

// ---------------- fused masked attention v2 ----------------
// |scores| ~ O(2) => exp without max-subtraction is safe in f32.
// Pass 1: QK^T MFMA once; store E' = edge*exp(s) as packed f16x2 in 64 VGPRs;
//         srow = sum exp(s). Pass 2: a = E'*sinv, LDS A-layout, PV MFMA.
__global__ __launch_bounds__(256) void attn_k2(
    const u16* __restrict__ Qb, const u16* __restrict__ Kb, const u16* __restrict__ Vb,
    const float* __restrict__ edge, float* __restrict__ ctx) {
  const int b = blockIdx.z, h = blockIdx.y, p0 = blockIdx.x * 64;
  const int tid = threadIdx.x;
  const int w = tid >> 6, lane = tid & 63, quad = lane >> 4, cidx = lane & 15;

  __shared__ __align__(16) u16 VTs[64][72];       // [d_local][c_local] V^T chunk
  __shared__ __align__(16) u16 attnS[4][16][40];  // per-wave C->A layout round-trip

  // Q frags direct from global (A-frag: m=lane&15, k=quad*8+j)
  const int qrow = w * 16 + cidx;
  const u16* qg = Qb + ((size_t)(b * PP + p0 + qrow)) * DD + h * DHH;
  const short8 qf0 = *(const short8*)(qg + quad * 8);
  const short8 qf1 = *(const short8*)(qg + 32 + quad * 8);

  const u16* Kbh = Kb + ((size_t)b * CCLUS * DD + h * DHH);
  const float* Ebp = edge + (size_t)(b * PP + p0 + w * 16) * CCLUS;

  float srow[4] = {0.f, 0.f, 0.f, 0.f};
  u32 es[64];  // 32 ct-tiles x 2 packed f16 pairs (rows r0r1, r2r3)

#pragma unroll
  for (int ct = 0; ct < 32; ct++) {
    const int c = ct * 16 + cidx;
    const u16* krow = Kbh + (size_t)c * DD;  // B-frag: n=lane&15, k=quad*8+j
    short8 kf0 = *(const short8*)(krow + quad * 8);
    short8 kf1 = *(const short8*)(krow + 32 + quad * 8);
    floatx4 s4 = {0.f, 0.f, 0.f, 0.f};
    s4 = mfma16(qf0, kf0, s4);
    s4 = mfma16(qf1, kf1, s4);
    float E[4];
#pragma unroll
    for (int r = 0; r < 4; r++) {
      float e = Ebp[(quad * 4 + r) * CCLUS + c];
      float sv = s4[r];
      float ex = (e > 0.f && sv == sv) ? __expf(fminf(sv, 15.f)) : 0.f;
      srow[r] += ex;
      E[r] = fminf(ex * e, 60000.f);  // stays finite in f16
    }
    es[ct * 2]     = packh2(E[0], E[1]);
    es[ct * 2 + 1] = packh2(E[2], E[3]);
  }
  // sum across the 16 lanes of each quad (same rows, disjoint cols)
#pragma unroll
  for (int off = 1; off < 16; off <<= 1)
#pragma unroll
    for (int r = 0; r < 4; r++) srow[r] += __shfl_xor(srow[r], off, 64);
  float sinv[4];
#pragma unroll
  for (int r = 0; r < 4; r++) sinv[r] = (srow[r] > 0.f) ? 1.0f / srow[r] : 0.f;

  floatx4 oacc[4];
#pragma unroll
  for (int nt = 0; nt < 4; nt++) oacc[nt] = (floatx4){0.f, 0.f, 0.f, 0.f};

#pragma unroll
  for (int cc2 = 0; cc2 < 8; cc2++) {
    __syncthreads();  // previous chunk's VTs reads done
#pragma unroll
    for (int i = 0; i < 2; i++) {
      int g = i * 256 + tid;
      int cl = g & 63, dblk = g >> 6;
      const u16* vg = Vb + ((size_t)(b * CCLUS + cc2 * 64 + cl) * DD + h * DHH + dblk * 8);
      short8 vv = *(const short8*)vg;
#pragma unroll
      for (int j = 0; j < 8; j++) VTs[dblk * 8 + j][cl] = ((const u16*)&vv)[j];
    }
    __syncthreads();

#pragma unroll
    for (int s = 0; s < 2; s++) {
#pragma unroll
      for (int t2 = 0; t2 < 2; t2++) {
        const int ct = cc2 * 4 + s * 2 + t2;
        const u32 p01 = es[ct * 2], p23 = es[ct * 2 + 1];
        attnS[w][quad * 4 + 0][t2 * 16 + cidx] = f2bf(h2f(p01) * sinv[0]);
        attnS[w][quad * 4 + 1][t2 * 16 + cidx] = f2bf(h2f(p01 >> 16) * sinv[1]);
        attnS[w][quad * 4 + 2][t2 * 16 + cidx] = f2bf(h2f(p23) * sinv[2]);
        attnS[w][quad * 4 + 3][t2 * 16 + cidx] = f2bf(h2f(p23 >> 16) * sinv[3]);
      }
      // wave-private LDS: per-wave DS ops are in-order; no barrier needed.
      short8 afr = *(const short8*)&attnS[w][cidx][quad * 8];
#pragma unroll
      for (int nt = 0; nt < 4; nt++) {
        short8 bfr = *(const short8*)&VTs[nt * 16 + cidx][s * 32 + quad * 8];
        oacc[nt] = mfma16(afr, bfr, oacc[nt]);
      }
    }
  }

#pragma unroll
  for (int nt = 0; nt < 4; nt++)
#pragma unroll
    for (int r = 0; r < 4; r++) {
      size_t off = (size_t)(b * PP + p0 + w * 16 + quad * 4 + r) * DD + h * DHH + nt * 16 + cidx;
      ctx[off] = oacc[nt][r];
    }
}

// ---------------- LayerNorm over D=1024 (f32 in-place on d_out) ----------------
__global__ __launch_bounds__(256) void ln_k(
    float* buf, const float* __restrict__ gamma, const float* __restrict__ beta) {
  const int row = blockIdx.x, tid = threadIdx.x;
  const int w = tid >> 6, lane = tid & 63;
  float* x = buf + (size_t)row * DD + tid * 4;
  float4 v = *(const float4*)x;
  float s = v.x + v.y + v.z + v.w;
  float sq = v.x * v.x + v.y * v.y + v.z * v.z + v.w * v.w;
#pragma unroll
  for (int off = 1; off < 64; off <<= 1) {
    s += __shfl_xor(s, off, 64);
    sq += __shfl_xor(sq, off, 64);
  }
  __shared__ float red[8];
  if (lane == 0) { red[w] = s; red[4 + w] = sq; }
  __syncthreads();
  s = red[0] + red[1] + red[2] + red[3];
  sq = red[4] + red[5] + red[6] + red[7];
  const float mu = s * (1.f / 1024.f);
  const float var = sq * (1.f / 1024.f) - mu * mu;
  const float rs = rsqrtf(fmaxf(var, 0.f) + 1e-6f);
  const float4 gr = *(const float4*)(gamma + tid * 4);
  const float4 br = *(const float4*)(beta + tid * 4);
  float4 y;
  y.x = (v.x - mu) * rs * gr.x + br.x;
  y.y = (v.y - mu) * rs * gr.y + br.y;
  y.z = (v.z - mu) * rs * gr.z + br.z;
  y.w = (v.w - mu) * rs * gr.w + br.w;
  *(float4*)x = y;
}

extern "C" void kernel_launch(void* const* d_in, const int* in_sizes, int n_in,
                              void* d_out, int out_size, void* d_ws, size_t ws_size,
                              hipStream_t stream) {
  const float* para    = (const float*)d_in[0];
  const float* cluster = (const float*)d_in[1];
  const float* edge    = (const float*)d_in[2];
  const float* Wq      = (const float*)d_in[3];
  const float* bq      = (const float*)d_in[4];
  const float* Wk      = (const float*)d_in[5];
  const float* bk      = (const float*)d_in[6];
  const float* Wv      = (const float*)d_in[7];
  const float* bv      = (const float*)d_in[8];
  const float* gamma   = (const float*)d_in[9];
  const float* beta    = (const float*)d_in[10];
  float* out = (float*)d_out;   // ctx lives here (attn writes f32, LN in-place)

  // bf16 workspace: 25M u16 = 50 MB
  u16* WqT = (u16*)d_ws;                        // 1M
  u16* WkT = WqT + (size_t)1024 * 1024;         // 1M
  u16* WvT = WkT + (size_t)1024 * 1024;         // 1M
  u16* Qb  = WvT + (size_t)1024 * 1024;         // 8M
  u16* Kb  = Qb  + (size_t)8192 * 1024;         // 2M
  u16* Vb  = Kb  + (size_t)2048 * 1024;         // 2M
  u16* Ap  = Vb  + (size_t)2048 * 1024;         // 8M (para bf16)
  u16* Ac  = Ap  + (size_t)8192 * 1024;         // 2M (cluster bf16)

  cast_k<<<dim3(2048), dim3(256), 0, stream>>>(para, cluster, Ap, Ac);
  transpose3_k<<<dim3(32, 32, 3), dim3(32, 32), 0, stream>>>(Wq, Wk, Wv, WqT, WkT, WvT);
  qkv_gemm3<<<dim3(96, 8), dim3(256), 0, stream>>>(Ap, Ac, WqT, WkT, WvT,
                                                   bq, bk, bv, Qb, Kb, Vb);
  attn_k2<<<dim3(PP / 64, HH, BB), dim3(256), 0, stream>>>(Qb, Kb, Vb, edge, out);
  ln_k<<<dim3(BB * PP), dim3(256), 0, stream>>>(out, gamma, beta);
}

// Round 8
// 303.572 us; speedup vs baseline: 1.3078x; 1.0139x over previous
//
#include <hip/hip_runtime.h>
#include <hip/hip_bf16.h>

#define BB 4
#define PP 2048
#define CCLUS 512
#define DD 1024
#define HH 16
#define DHH 64

typedef __attribute__((ext_vector_type(8))) short short8;
typedef __attribute__((ext_vector_type(4))) float floatx4;
typedef unsigned short u16;
typedef unsigned int u32;
typedef unsigned long long u64;

__device__ __forceinline__ float bf2f(u16 u) {
  union { u32 i; float f; } v; v.i = ((u32)u) << 16; return v.f;
}
__device__ __forceinline__ u16 f2bf(float f) {
  union { float f; u32 i; } v; v.f = f;
  u32 x = v.i;
  return (u16)((x + 0x7fffu + ((x >> 16) & 1u)) >> 16);  // RNE
}
__device__ __forceinline__ u64 pack4(float a, float b, float c, float d) {
  return (u64)f2bf(a) | ((u64)f2bf(b) << 16) | ((u64)f2bf(c) << 32) | ((u64)f2bf(d) << 48);
}

__device__ __forceinline__ floatx4 mfma16(short8 a, short8 b, floatx4 c) {
  return __builtin_amdgcn_mfma_f32_16x16x32_bf16(a, b, c, 0, 0, 0);
}

// async global->LDS, 16B/lane; LDS dest = wave-uniform base + lane*16 (m97)
__device__ __forceinline__ void gload_lds16(const u16* g, u16* l) {
  __builtin_amdgcn_global_load_lds(
      (const __attribute__((address_space(1))) u32*)g,
      (__attribute__((address_space(3))) u32*)l, 16, 0, 0);
}

// ---------------- f32 -> bf16 cast for para & cluster ----------------
__global__ __launch_bounds__(256) void cast_k(
    const float* __restrict__ para, const float* __restrict__ cluster,
    u16* __restrict__ Ap, u16* __restrict__ Ac) {
  const int NP4 = (BB * PP * DD) / 4;
  const int NC4 = (BB * CCLUS * DD) / 4;
  const int stride = gridDim.x * blockDim.x;
  for (int i = blockIdx.x * blockDim.x + threadIdx.x; i < NP4 + NC4; i += stride) {
    const float* src; u16* dst; int j;
    if (i < NP4) { src = para; dst = Ap; j = i; }
    else         { src = cluster; dst = Ac; j = i - NP4; }
    const float4 v = *(const float4*)(src + (size_t)j * 4);
    *(u64*)(dst + (size_t)j * 4) = pack4(v.x, v.y, v.z, v.w);
  }
}

// ---------------- transpose+cast Wq/Wk/Wv (1024x1024 f32 -> bf16^T) ----------------
__global__ __launch_bounds__(1024) void transpose3_k(
    const float* __restrict__ Wq, const float* __restrict__ Wk, const float* __restrict__ Wv,
    u16* __restrict__ WqT, u16* __restrict__ WkT, u16* __restrict__ WvT) {
  __shared__ u16 tile[32][33];
  const int z = blockIdx.z;
  const float* src = (z == 0) ? Wq : (z == 1) ? Wk : Wv;
  u16* dst = (z == 0) ? WqT : (z == 1) ? WkT : WvT;
  int x = blockIdx.x * 32 + threadIdx.x;
  int y = blockIdx.y * 32 + threadIdx.y;
  tile[threadIdx.y][threadIdx.x] = f2bf(src[y * DD + x]);
  __syncthreads();
  x = blockIdx.y * 32 + threadIdx.x;
  y = blockIdx.x * 32 + threadIdx.y;
  dst[y * DD + x] = tile[threadIdx.x][threadIdx.y];
}

// ---------------- fused QKV GEMM (m97 global_load_lds staging) ----------------
// C[M,1024] = (A_bf16 @ BT_bf16^T + bias)*scale, bf16 out. 128x128, BK=32.
// packed grid.x=96: [0,64)=Q, [64,80)=K, [80,96)=V.
__global__ __launch_bounds__(256) void qkv_gemm3(
    const u16* __restrict__ Ap, const u16* __restrict__ Ac,
    const u16* __restrict__ WqT, const u16* __restrict__ WkT, const u16* __restrict__ WvT,
    const float* __restrict__ bq, const float* __restrict__ bk, const float* __restrict__ bv,
    u16* __restrict__ Qb, u16* __restrict__ Kb, u16* __restrict__ Vb) {
  const int bx = blockIdx.x;
  const u16* A; const u16* BT; const float* bias; u16* Cout; float scale; int mt;
  if (bx < 64)      { A = Ap; BT = WqT; bias = bq; Cout = Qb; scale = 0.125f; mt = bx; }
  else if (bx < 80) { A = Ac; BT = WkT; bias = bk; Cout = Kb; scale = 1.0f;   mt = bx - 64; }
  else              { A = Ac; BT = WvT; bias = bv; Cout = Vb; scale = 1.0f;   mt = bx - 80; }

  __shared__ __align__(16) u16 As[128 * 32];
  __shared__ __align__(16) u16 Bs[128 * 32];

  const int tid = threadIdx.x;
  const int w = tid >> 6, lane = tid & 63, quad = lane >> 4, cidx = lane & 15;
  const int wy = w >> 1, wx = w & 1;
  const int m0 = mt * 128, n0 = blockIdx.y * 128;

  floatx4 acc[4][4];
#pragma unroll
  for (int i = 0; i < 4; i++)
#pragma unroll
    for (int j = 0; j < 4; j++) acc[i][j] = (floatx4){0.f, 0.f, 0.f, 0.f};

  const int row0 = tid >> 2, kc0 = tid & 3;
  const int offG0 = row0 * 1024 + kc0 * 8;
  const int offG1 = (row0 + 64) * 1024 + kc0 * 8;
  u16* ldsA0 = As + (size_t)(w * 64) * 8;
  u16* ldsA1 = As + (size_t)(w * 64 + 256) * 8;
  u16* ldsB0 = Bs + (size_t)(w * 64) * 8;
  u16* ldsB1 = Bs + (size_t)(w * 64 + 256) * 8;

  const u16* Abase = A + (size_t)m0 * 1024;
  const u16* Bbase = BT + (size_t)n0 * 1024;

  for (int kt = 0; kt < 32; kt++) {
    const u16* Ak = Abase + kt * 32;
    const u16* Bk = Bbase + kt * 32;
    gload_lds16(Ak + offG0, ldsA0);
    gload_lds16(Ak + offG1, ldsA1);
    gload_lds16(Bk + offG0, ldsB0);
    gload_lds16(Bk + offG1, ldsB1);
    __syncthreads();

    short8 af[4], bfr[4];
#pragma unroll
    for (int i = 0; i < 4; i++) {
      int ra = wy * 64 + i * 16 + cidx;
      af[i] = *(const short8*)&As[ra * 32 + quad * 8];
      int rb = wx * 64 + i * 16 + cidx;
      bfr[i] = *(const short8*)&Bs[rb * 32 + quad * 8];
    }
#pragma unroll
    for (int mi = 0; mi < 4; mi++)
#pragma unroll
      for (int ni = 0; ni < 4; ni++)
        acc[mi][ni] = mfma16(af[mi], bfr[ni], acc[mi][ni]);
    __syncthreads();
  }

#pragma unroll
  for (int ni = 0; ni < 4; ni++) {
    const int ncol = n0 + wx * 64 + ni * 16 + cidx;
    const float bvv = bias[ncol];
#pragma unroll
    for (int mi = 0; mi < 4; mi++) {
      const int mrow = m0 + wy * 64 + mi * 16 + quad * 4;
#pragma unroll
      for (int r = 0; r < 4; r++) {
        float v = (acc[mi][ni][r] + bvv) * scale;
        Cout[(size_t)(mrow + r) * 1024 + ncol] = f2bf(v);
      }
    }
  }
}

// ---------------- fused masked attention v3: S^T MFMA, single pass ----------------
// S^T = K·Q^T  (A=K: m=c,k=d; B=Q: n=p,k=d). Lane owns S^T[c=quad*4+r][p=cidx]:
//  -> edge is a float4 (4 consecutive c), attnS write is one b64.
// Unnormalized E'=edge*exp(s) accumulated through PV; oacc scaled by 1/srow at end.
__global__ __launch_bounds__(256) void attn_k3(
    const u16* __restrict__ Qb, const u16* __restrict__ Kb, const u16* __restrict__ Vb,
    const float* __restrict__ edge, float* __restrict__ ctx) {
  const int b = blockIdx.z, h = blockIdx.y, p0 = blockIdx.x * 64;
  const int tid = threadIdx.x;
  const int w = tid >> 6, lane = tid & 63, quad = lane >> 4, cidx = lane & 15;

  __shared__ __align__(16) u16 VTs[64][72];       // [d_local][c_local] V^T chunk
  __shared__ __align__(16) u16 attnS[4][16][40];  // per-wave [p_local][c_local(32)]
  __shared__ float sred[4][16];                   // per-wave sinv bounce

  // Q frags (B-operand: n=cidx -> p row, k=quad*8+j)
  const int prow = w * 16 + cidx;
  const u16* qg = Qb + ((size_t)(b * PP + p0 + prow)) * DD + h * DHH;
  const short8 qf0 = *(const short8*)(qg + quad * 8);
  const short8 qf1 = *(const short8*)(qg + 32 + quad * 8);

  const u16* Kbh = Kb + ((size_t)b * CCLUS * DD + h * DHH);
  const float* Erow = edge + (size_t)(b * PP + p0 + prow) * CCLUS;  // lane's p row

  float srow = 0.f;  // sum over c of exp(s) for p=prow (partial per quad)
  floatx4 oacc[4];
#pragma unroll
  for (int nt = 0; nt < 4; nt++) oacc[nt] = (floatx4){0.f, 0.f, 0.f, 0.f};

  for (int cc2 = 0; cc2 < 8; cc2++) {
    __syncthreads();  // previous chunk's VTs/attnS reads done
    // stage V^T chunk [d][c] (64x64)
#pragma unroll
    for (int i = 0; i < 2; i++) {
      int g = i * 256 + tid;
      int cl = g & 63, dblk = g >> 6;
      const u16* vg = Vb + ((size_t)(b * CCLUS + cc2 * 64 + cl) * DD + h * DHH + dblk * 8);
      short8 vv = *(const short8*)vg;
#pragma unroll
      for (int j = 0; j < 8; j++) VTs[dblk * 8 + j][cl] = ((const u16*)&vv)[j];
    }
    __syncthreads();

#pragma unroll
    for (int s = 0; s < 2; s++) {
#pragma unroll
      for (int t2 = 0; t2 < 2; t2++) {
        const int cbase = (cc2 * 4 + s * 2 + t2) * 16;
        // K A-frag: m=cidx -> c=cbase+cidx, k=quad*8+j
        const u16* krow = Kbh + (size_t)(cbase + cidx) * DD;
        short8 kf0 = *(const short8*)(krow + quad * 8);
        short8 kf1 = *(const short8*)(krow + 32 + quad * 8);
        floatx4 s4 = {0.f, 0.f, 0.f, 0.f};
        s4 = mfma16(kf0, qf0, s4);
        s4 = mfma16(kf1, qf1, s4);
        // lane owns S^T[c=cbase+quad*4+r][p=prow]; edge float4 at (prow, cbase+quad*4)
        const float4 e4 = *(const float4*)(Erow + cbase + quad * 4);
        float E[4];
#pragma unroll
        for (int r = 0; r < 4; r++) {
          float e = (&e4.x)[r];
          float sv = s4[r];
          float ex = (e > 0.f && sv == sv) ? __expf(fminf(sv, 15.f)) : 0.f;
          srow += ex;
          E[r] = ex * e;  // <= 3.3e6, fine in bf16
        }
        *(u64*)&attnS[w][cidx][t2 * 16 + quad * 4] = pack4(E[0], E[1], E[2], E[3]);
      }
      // PV: A-frag = attnS[p=cidx][c=quad*8+j] (wave-private LDS, in-order)
      short8 afr = *(const short8*)&attnS[w][cidx][quad * 8];
#pragma unroll
      for (int nt = 0; nt < 4; nt++) {
        short8 bfr = *(const short8*)&VTs[nt * 16 + cidx][s * 32 + quad * 8];
        oacc[nt] = mfma16(afr, bfr, oacc[nt]);
      }
    }
  }

  // reduce srow across quads (lane^16, lane^32 hold same p, disjoint c)
  srow += __shfl_xor(srow, 16, 64);
  srow += __shfl_xor(srow, 32, 64);
  const float sinv = (srow > 0.f) ? 1.0f / srow : 0.f;
  // redistribute p-indexed sinv into C-layout rows (p = quad*4+r)
  sred[w][cidx] = sinv;                       // wave-private, DS in-order
  const float4 sv4 = *(const float4*)&sred[w][quad * 4];

#pragma unroll
  for (int nt = 0; nt < 4; nt++)
#pragma unroll
    for (int r = 0; r < 4; r++) {
      size_t off = (size_t)(b * PP + p0 + w * 16 + quad * 4 + r) * DD + h * DHH + nt * 16 + cidx;
      ctx[off] = oacc[nt][r] * (&sv4.x)[r];
    }
}

// ---------------- LayerNorm over D=1024 (f32 in-place on d_out) ----------------
__global__ __launch_bounds__(256) void ln_k(
    float* buf, const float* __restrict__ gamma, const float* __restrict__ beta) {
  const int row = blockIdx.x, tid = threadIdx.x;
  const int w = tid >> 6, lane = tid & 63;
  float* x = buf + (size_t)row * DD + tid * 4;
  float4 v = *(const float4*)x;
  float s = v.x + v.y + v.z + v.w;
  float sq = v.x * v.x + v.y * v.y + v.z * v.z + v.w * v.w;
#pragma unroll
  for (int off = 1; off < 64; off <<= 1) {
    s += __shfl_xor(s, off, 64);
    sq += __shfl_xor(sq, off, 64);
  }
  __shared__ float red[8];
  if (lane == 0) { red[w] = s; red[4 + w] = sq; }
  __syncthreads();
  s = red[0] + red[1] + red[2] + red[3];
  sq = red[4] + red[5] + red[6] + red[7];
  const float mu = s * (1.f / 1024.f);
  const float var = sq * (1.f / 1024.f) - mu * mu;
  const float rs = rsqrtf(fmaxf(var, 0.f) + 1e-6f);
  const float4 gr = *(const float4*)(gamma + tid * 4);
  const float4 br = *(const float4*)(beta + tid * 4);
  float4 y;
  y.x = (v.x - mu) * rs * gr.x + br.x;
  y.y = (v.y - mu) * rs * gr.y + br.y;
  y.z = (v.z - mu) * rs * gr.z + br.z;
  y.w = (v.w - mu) * rs * gr.w + br.w;
  *(float4*)x = y;
}

extern "C" void kernel_launch(void* const* d_in, const int* in_sizes, int n_in,
                              void* d_out, int out_size, void* d_ws, size_t ws_size,
                              hipStream_t stream) {
  const float* para    = (const float*)d_in[0];
  const float* cluster = (const float*)d_in[1];
  const float* edge    = (const float*)d_in[2];
  const float* Wq      = (const float*)d_in[3];
  const float* bq      = (const float*)d_in[4];
  const float* Wk      = (const float*)d_in[5];
  const float* bk      = (const float*)d_in[6];
  const float* Wv      = (const float*)d_in[7];
  const float* bv      = (const float*)d_in[8];
  const float* gamma   = (const float*)d_in[9];
  const float* beta    = (const float*)d_in[10];
  float* out = (float*)d_out;   // ctx lives here (attn writes f32, LN in-place)

  // bf16 workspace: 25M u16 = 50 MB
  u16* WqT = (u16*)d_ws;                        // 1M
  u16* WkT = WqT + (size_t)1024 * 1024;         // 1M
  u16* WvT = WkT + (size_t)1024 * 1024;         // 1M
  u16* Qb  = WvT + (size_t)1024 * 1024;         // 8M
  u16* Kb  = Qb  + (size_t)8192 * 1024;         // 2M
  u16* Vb  = Kb  + (size_t)2048 * 1024;         // 2M
  u16* Ap  = Vb  + (size_t)2048 * 1024;         // 8M (para bf16)
  u16* Ac  = Ap  + (size_t)8192 * 1024;         // 2M (cluster bf16)

  cast_k<<<dim3(2048), dim3(256), 0, stream>>>(para, cluster, Ap, Ac);
  transpose3_k<<<dim3(32, 32, 3), dim3(32, 32), 0, stream>>>(Wq, Wk, Wv, WqT, WkT, WvT);
  qkv_gemm3<<<dim3(96, 8), dim3(256), 0, stream>>>(Ap, Ac, WqT, WkT, WvT,
                                                   bq, bk, bv, Qb, Kb, Vb);
  attn_k3<<<dim3(PP / 64, HH, BB), dim3(256), 0, stream>>>(Qb, Kb, Vb, edge, out);
  ln_k<<<dim3(BB * PP), dim3(256), 0, stream>>>(out, gamma, beta);
}